// Round 10
// baseline (199.457 us; speedup 1.0000x reference)
//
#include <hip/hip_runtime.h>

typedef __attribute__((ext_vector_type(8))) short short8;
typedef __attribute__((ext_vector_type(16))) float f32x16;

// ws layout:
//   Ft2  [z=512][yy=66][xx=66][8] bf16 halo-padded features, z = c*8 + b   (35.68 MB)
//   wt2  [i=576][n=128][8] bf16 B, i-major (i = c*9 + kh*3 + kw)           (1.18 MB)
#define FT2_SHORTS (512u * 4356u * 8u)
#define PLANE16    4356

__device__ __forceinline__ unsigned short f2bf(float x) {
    union { float f; unsigned u; } v; v.f = x;
    unsigned r = v.u + 0x7FFFu + ((v.u >> 16) & 1u);   // RNE bf16
    return (unsigned short)(r >> 16);
}

__device__ __forceinline__ void feat8(float p, unsigned short* uf) {
    float e   = __expf(-p);
    float sig = 1.f / (1.f + e);
    uf[0] = f2bf(p * sig);
    float u  = p * 1.5f + 4.5f;
    float fj = floorf(u);
    int   j0 = (int)fj;
    float t  = u - fj;
    bool  inr = (u >= 0.f) && (u < 9.f);
    float t2 = t * t, t3 = t2 * t;
    const float c16 = 1.f / 6.f;
    float r0 = t3 * c16;
    float r1 = (-3.f * t3 + 3.f * t2 + 3.f * t + 1.f) * c16;
    float r2 = (3.f * t3 - 6.f * t2 + 4.f) * c16;
    float s1 = 1.f - t;
    float r3 = s1 * s1 * s1 * c16;
#pragma unroll
    for (int g = 0; g < 6; ++g) {
        int r = j0 - g;
        float v = (r == 0) ? r0 : ((r == 1) ? r1 : ((r == 2) ? r2 : ((r == 3) ? r3 : 0.f)));
        uf[1 + g] = f2bf(inr ? v : 0.f);
    }
    uf[7] = 0;
}

// ---- Fused prep: per block (512): 144 B-chunks + 1 halo plane + 1 feature line ----
__global__ __launch_bounds__(256)
void prep_all(const float* __restrict__ x,
              const float* __restrict__ bw, const float* __restrict__ sw,
              unsigned short* __restrict__ ft, unsigned short* __restrict__ wt) {
    const int blk = blockIdx.x;          // 0..511
    const int tid = threadIdx.x;

    // (1) B prep into i-major layout: wt[i][n][8]
    if (tid < 144) {
        int idx = blk * 144 + tid;
        int o = idx / 576;
        int i = idx - o * 576;
        union { unsigned short u[8]; uint4 v; } pk;
        pk.u[0] = f2bf(bw[o * 576 + i]);
        const float* s = sw + (size_t)(o * 576 + i) * 6;
#pragma unroll
        for (int f = 0; f < 6; ++f) pk.u[1 + f] = f2bf(s[f]);
        pk.u[7] = 0;
        *(uint4*)(wt + ((size_t)i * 1024 + o * 8)) = pk.v;
    }

    // (2) halo plane z = blk: feat8(0) into the 260 border cells
    {
        short8 pad = { 0, 0, (short)0x3CAB, (short)0x3EF5,
                       (short)0x3EF5, (short)0x3CAB, 0, 0 };
        for (int t = tid; t < 260; t += 256) {
            int yy, xx;
            if (t < 66)       { yy = 0;       xx = t; }
            else if (t < 132) { yy = 65;      xx = t - 66; }
            else if (t < 196) { yy = t - 131; xx = 0; }
            else              { yy = t - 195; xx = 65; }
            ((short8*)ft)[blk * PLANE16 + yy * 66 + xx] = pad;
        }
    }

    // (3) features for line = blk (b = blk>>6, y = blk&63)
    __shared__ float Xl[64 * 65];
    const int b = blk >> 6, y = blk & 63;
    const float* xl = x + (size_t)blk * 4096;
    for (int f4 = tid; f4 < 1024; f4 += 256) {
        float4 v = ((const float4*)xl)[f4];
        int xx = f4 >> 4, c4 = (f4 & 15) << 2;
        float* d = &Xl[xx * 65 + c4];
        d[0] = v.x; d[1] = v.y; d[2] = v.z; d[3] = v.w;
    }
    __syncthreads();
    const int xx = tid & 63;
    const int cw = tid >> 6;
#pragma unroll 4
    for (int p = 0; p < 16; ++p) {
        int c = cw + (p << 2);
        float pv = Xl[xx * 65 + c];
        union { unsigned short u[8]; uint4 v; } pk;
        feat8(pv, pk.u);
        size_t o16 = (size_t)(c * 8 + b) * PLANE16 + (y + 1) * 66 + (xx + 1);
        *(uint4*)(ft + (o16 << 3)) = pk.v;
    }
}

// ---- Main GEMM: BARRIER-FREE all-register K-loop, 3 waves/SIMD ----
// R9 (2 waves/SIMD, clean counters) proved the loop is LATENCY-bound: all
// pipes idle (MfmaUtil 25, VALU 10, HBM 8, Occ 19), T ~= steps x lat/depth.
// This round: block 768 = 12 waves -> 3 waves/SIMD (launch_bounds(768,3),
// 170-reg cap). To fit: the 9 per-lane A-step offsets become constexpr
// literals selected on h per use (rematerializable, no live registers);
// 'can' eliminated. kq 0..2 strides c-pairs by 3 (11/11/10 pairs; imbalance
// absorbed by the 3-way epilogue reduction). Per-CU loaded bytes unchanged.
#define DZ3 3345408u   // A base advance per stride-3 c-pair (48 planes x 69696 B)

__host__ __device__ constexpr int AOC(int t) {
    // (co,kh,kw) decode of K16-chunk t (0..17) -> byte offset within c-pair
    return ((t >= 9) ? 557568 : 0)
         + (((((t - ((t >= 9) ? 9 : 0)) * 11) >> 5) * 66
            + ((t - ((t >= 9) ? 9 : 0)) - ((((t - ((t >= 9) ? 9 : 0)) * 11) >> 5) * 3))) * 16);
}
#define AOFF(S2) (h ? AOC(2 * (S2) + 1) : AOC(2 * (S2)))

#define MFMA4(P)                                                                      \
    acc00 = __builtin_amdgcn_mfma_f32_32x32x16_bf16(P##a0, P##b0, acc00, 0, 0, 0);    \
    acc01 = __builtin_amdgcn_mfma_f32_32x32x16_bf16(P##a0, P##b1, acc01, 0, 0, 0);    \
    acc10 = __builtin_amdgcn_mfma_f32_32x32x16_bf16(P##a1, P##b0, acc10, 0, 0, 0);    \
    acc11 = __builtin_amdgcn_mfma_f32_32x32x16_bf16(P##a1, P##b1, acc11, 0, 0, 0);

#define ISS(P, CAX, S2) {                                                             \
    const int ao_ = AOFF(S2);                                                         \
    P##a0 = *(const short8*)(ftc + (CAX) + ao_);                                      \
    P##a1 = *(const short8*)(ftc + (CAX) + ao_ + 512);                                \
    P##b0 = *(const short8*)(wtc + bv);                                               \
    P##b1 = *(const short8*)(wtc + bv + 512);                                         \
    bv += 4096u; }

// One c-pair: 9 K16 steps, slots alternate SA,SB,...; issue depth = 2 steps.
#define PAIR(SA, SB, CAX, CAN, LAST)                                                  \
    MFMA4(SA) ISS(SA, CAX, 2)                                                         \
    MFMA4(SB) ISS(SB, CAX, 3)                                                         \
    MFMA4(SA) ISS(SA, CAX, 4)                                                         \
    MFMA4(SB) ISS(SB, CAX, 5)                                                         \
    MFMA4(SA) ISS(SA, CAX, 6)                                                         \
    MFMA4(SB) ISS(SB, CAX, 7)                                                         \
    MFMA4(SA) ISS(SA, CAX, 8)                                                         \
    bv += 73728u;  /* skip 2 c-pairs (stride-3 kq interleave) */                      \
    MFMA4(SB) if (!(LAST)) { ISS(SB, CAN, 0) }                                        \
    MFMA4(SA) if (!(LAST)) { ISS(SA, CAN, 1) }

// Epilogue reduce helpers: conflict-free float4 layout (lane-stride 16 B).
#define DUMPA(base_, A_)                                                              \
    {   float4* s4 = (float4*)(red + (base_));                                        \
        _Pragma("unroll")                                                             \
        for (int c = 0; c < 4; ++c)                                                   \
            s4[c * 64 + lane] = make_float4(A_[4*c], A_[4*c+1], A_[4*c+2], A_[4*c+3]); }
#define ADDA(base_, A_)                                                               \
    {   const float4* s4 = (const float4*)(red + (base_));                            \
        _Pragma("unroll")                                                             \
        for (int c = 0; c < 4; ++c) {                                                 \
            float4 rv = s4[c * 64 + lane];                                            \
            A_[4*c] += rv.x; A_[4*c+1] += rv.y; A_[4*c+2] += rv.z; A_[4*c+3] += rv.w; } }

__global__ __launch_bounds__(768, 3)
void convkan_gemm(const unsigned short* __restrict__ ft,
                  const unsigned short* __restrict__ wt,
                  const float* __restrict__ bias,
                  float* __restrict__ out) {
    extern __shared__ float red[];               // 128 KB, epilogue only

    const int tid  = threadIdx.x;
    const int blk  = blockIdx.x;                 // 0..255
    const int mb   = ((blk & 7) << 5) | (blk >> 3);  // XCD swizzle: XCD owns image
    const int lane = tid & 63;
    const int wave = tid >> 6;                   // 0..11
    const int kq   = wave >> 2;                  // K-third (c-pair stride-3) 0..2
    const int mh   = (wave >> 1) & 1;            // line within 2-line tile
    const int nh   = wave & 1;                   // n-half (64 ch)
    const int l32  = lane & 31;
    const int h    = lane >> 5;                  // k-half within MFMA K16

    const int b  = mb >> 5;                      // image 0..7
    const int y0 = (mb & 31) << 1;               // first of 2 lines

    const char* ftc = (const char*)ft;
    const char* wtc = (const char*)wt;

    // running bases (32-bit byte offsets); pair p covers c = 2p, 2p+1
    unsigned cax = ((unsigned)((16 * kq + b) * PLANE16 + (y0 + mh) * 66 + l32)) << 4;
    unsigned bv  = ((unsigned)(18 * kq + h) << 11) + (((unsigned)(nh * 64 + l32)) << 4);

    f32x16 acc00, acc01, acc10, acc11;
#pragma unroll
    for (int e = 0; e < 16; ++e) { acc00[e] = 0.f; acc01[e] = 0.f; acc10[e] = 0.f; acc11[e] = 0.f; }

    short8 Aa0, Aa1, Ab0, Ab1;                   // slot A
    short8 Ba0, Ba1, Bb0, Bb1;                   // slot B

    // prologue: issue steps 0,1 of c-pair kq
    ISS(A, cax, 0)
    ISS(B, cax, 1)

    // 8 pairs (4 double-pairs), parity static across the loop body
    for (int w = 0; w < 4; ++w) {
        PAIR(A, B, cax, cax + DZ3, 0) cax += DZ3;
        PAIR(B, A, cax, cax + DZ3, 0) cax += DZ3;
    }
    // tail: kq 0,1 -> 3 more pairs (11 total); kq 2 -> 2 more (10 total)
    if (kq < 2) {
        PAIR(A, B, cax, cax + DZ3, 0) cax += DZ3;
        PAIR(B, A, cax, cax + DZ3, 0) cax += DZ3;
        PAIR(A, B, cax, cax, 1)
    } else {
        PAIR(A, B, cax, cax + DZ3, 0) cax += DZ3;
        PAIR(B, A, cax, cax, 1)
    }

    // ---- K-partial reduction across kq (one round, 2 source regions) ----
    __syncthreads();
    const int grp = mh * 2 + nh;                 // 0..3

    if (kq != 0) {
        const int rb = ((kq - 1) * 4 + grp) * 4096;
        DUMPA(rb,        acc00); DUMPA(rb + 1024, acc01);
        DUMPA(rb + 2048, acc10); DUMPA(rb + 3072, acc11);
    }
    __syncthreads();
    if (kq == 0) {
        const int r1 = grp * 4096, r2 = (4 + grp) * 4096;
        ADDA(r1,        acc00); ADDA(r1 + 1024, acc01);
        ADDA(r1 + 2048, acc10); ADDA(r1 + 3072, acc11);
        ADDA(r2,        acc00); ADDA(r2 + 1024, acc01);
        ADDA(r2 + 2048, acc10); ADDA(r2 + 3072, acc11);

        const int ncol = nh * 64 + l32;
        const float bv0 = bias[ncol];
        const float bv1 = bias[ncol + 32];
        const int prow = mb * 128 + mh * 64;
#pragma unroll
        for (int r = 0; r < 16; ++r) {
            int mrow = (r & 3) + ((r >> 2) << 3) + 4 * h;
            float* p = out + (size_t)(prow + mrow) * 128 + ncol;
            p[0]  = acc00[r] + bv0;
            p[32] = acc01[r] + bv1;
            float* p2 = out + (size_t)(prow + 32 + mrow) * 128 + ncol;
            p2[0]  = acc10[r] + bv0;
            p2[32] = acc11[r] + bv1;
        }
    }
}

extern "C" void kernel_launch(void* const* d_in, const int* in_sizes, int n_in,
                              void* d_out, int out_size, void* d_ws, size_t ws_size,
                              hipStream_t stream) {
    (void)in_sizes; (void)n_in; (void)ws_size; (void)out_size;
    const float* x        = (const float*)d_in[0];
    const float* base_w   = (const float*)d_in[1];
    const float* spline_w = (const float*)d_in[2];
    const float* bias     = (const float*)d_in[3];
    float* out = (float*)d_out;

    unsigned short* ft = (unsigned short*)d_ws;      // 35.68 MB halo features
    unsigned short* wt = ft + FT2_SHORTS;            // 1.18 MB tiled B (i-major)

    hipLaunchKernelGGL(prep_all, dim3(512), dim3(256), 0, stream,
                       x, base_w, spline_w, ft, wt);

    const int shmem = 32768 * 4;                     // 128 KB (epilogue reduction)
    (void)hipFuncSetAttribute((const void*)convkan_gemm,
                              hipFuncAttributeMaxDynamicSharedMemorySize, shmem);
    hipLaunchKernelGGL(convkan_gemm, dim3(256), dim3(768), shmem, stream,
                       ft, wt, bias, out);
}

// Round 11
// 129.887 us; speedup vs baseline: 1.5356x; 1.5356x over previous
//
#include <hip/hip_runtime.h>

typedef __attribute__((ext_vector_type(8))) short short8;
typedef __attribute__((ext_vector_type(16))) float f32x16;

// ws layout:
//   Ft2  [z=512][yy=66][xx=66][8] bf16 halo-padded features, z = c*8 + b   (35.68 MB)
//   wt2  [slab=72][e=8][n=128][8] bf16 B slabs, e = i&7 (chunk-major)      (1.18 MB)
#define FT2_SHORTS (512u * 4356u * 8u)
#define PLANE16    4356

typedef __attribute__((address_space(3))) unsigned int lds_u32_t;
typedef __attribute__((address_space(1))) const unsigned int g_u32_t;

__device__ __forceinline__ unsigned short f2bf(float x) {
    union { float f; unsigned u; } v; v.f = x;
    unsigned r = v.u + 0x7FFFu + ((v.u >> 16) & 1u);   // RNE bf16
    return (unsigned short)(r >> 16);
}

__device__ __forceinline__ void feat8(float p, unsigned short* uf) {
    float e   = __expf(-p);
    float sig = 1.f / (1.f + e);
    uf[0] = f2bf(p * sig);
    float u  = p * 1.5f + 4.5f;
    float fj = floorf(u);
    int   j0 = (int)fj;
    float t  = u - fj;
    bool  inr = (u >= 0.f) && (u < 9.f);
    float t2 = t * t, t3 = t2 * t;
    const float c16 = 1.f / 6.f;
    float r0 = t3 * c16;
    float r1 = (-3.f * t3 + 3.f * t2 + 3.f * t + 1.f) * c16;
    float r2 = (3.f * t3 - 6.f * t2 + 4.f) * c16;
    float s1 = 1.f - t;
    float r3 = s1 * s1 * s1 * c16;
#pragma unroll
    for (int g = 0; g < 6; ++g) {
        int r = j0 - g;
        float v = (r == 0) ? r0 : ((r == 1) ? r1 : ((r == 2) ? r2 : ((r == 3) ? r3 : 0.f)));
        uf[1 + g] = f2bf(inr ? v : 0.f);
    }
    uf[7] = 0;
}

// ---- Prep v2: THROUGHPUT rewrite. Grid 2048 x 256 (8 blocks/CU, 4x waves),
// no LDS, no syncthreads, no dependent chains. Block = (line 0..511, q 0..3).
// Each thread: one float4 x-read (4 consecutive channels, 16B aligned), 4
// independent feat8 -> 4 coalesced 1-KB bursts. Halo (65 cells) and B-prep
// (36 chunks) spread per block. Old prep was ~45-60 us (6x over its ~8 us BW
// floor: 8 waves/CU + serial 16-deep LDS->feat8->store chain); this removes
// every one of those limiters.
__global__ __launch_bounds__(256)
void prep_all(const float* __restrict__ x,
              const float* __restrict__ bw, const float* __restrict__ sw,
              unsigned short* __restrict__ ft, unsigned short* __restrict__ wt) {
    const int blk  = blockIdx.x;         // 0..2047
    const int tid  = threadIdx.x;
    const int line = blk >> 2;           // 0..511 (also halo plane z)
    const int q    = blk & 3;            // channel quarter

    // (1) B prep into slab-chunk-major layout: wt[slab][i&7][n][8]
    if (tid < 36) {
        int idx = blk * 36 + tid;        // 2048*36 = 73728 = 576*128
        int o = idx / 576;
        int i = idx - o * 576;
        int slab = i >> 3, e = i & 7;
        union { unsigned short u[8]; uint4 v; } pk;
        pk.u[0] = f2bf(bw[o * 576 + i]);
        const float* s = sw + (size_t)(o * 576 + i) * 6;
#pragma unroll
        for (int f = 0; f < 6; ++f) pk.u[1 + f] = f2bf(s[f]);
        pk.u[7] = 0;
        *(uint4*)(wt + ((size_t)slab * 8192 + e * 1024 + o * 8)) = pk.v;
    }

    // (2) halo plane z = line: 260 border cells split 65 per quarter
    if (tid < 65) {
        int t = q * 65 + tid;            // 0..259
        short8 pad = { 0, 0, (short)0x3CAB, (short)0x3EF5,
                       (short)0x3EF5, (short)0x3CAB, 0, 0 };
        int yy, xx;
        if (t < 66)       { yy = 0;       xx = t; }
        else if (t < 132) { yy = 65;      xx = t - 66; }
        else if (t < 196) { yy = t - 131; xx = 0; }
        else              { yy = t - 195; xx = 65; }
        ((short8*)ft)[line * PLANE16 + yy * 66 + xx] = pad;
    }

    // (3) features: thread (xx, cw) handles channels c0..c0+3 of pixel (line, xx)
    const int xx = tid & 63;
    const int cw = tid >> 6;             // 0..3
    const int b  = line >> 6, y = line & 63;
    const int c0 = q * 16 + cw * 4;
    const float4 v = *(const float4*)(x + (size_t)line * 4096 + xx * 64 + c0);

    union { unsigned short u[8]; uint4 w; } p0, p1, p2, p3;
    feat8(v.x, p0.u); feat8(v.y, p1.u); feat8(v.z, p2.u); feat8(v.w, p3.u);

    const size_t cell = (size_t)(y + 1) * 66 + (xx + 1);
    *(uint4*)(ft + ((((size_t)((c0 + 0) * 8 + b) * PLANE16) + cell) << 3)) = p0.w;
    *(uint4*)(ft + ((((size_t)((c0 + 1) * 8 + b) * PLANE16) + cell) << 3)) = p1.w;
    *(uint4*)(ft + ((((size_t)((c0 + 2) * 8 + b) * PLANE16) + cell) << 3)) = p2.w;
    *(uint4*)(ft + ((((size_t)((c0 + 3) * 8 + b) * PLANE16) + cell) << 3)) = p3.w;
}

// ---- Main GEMM (R6 verbatim — best measured: 56.7 us, clean counters) ----
// tile 64m(1 line) x 128n, FULL K, grid 512, block 512 (8 waves), 2 blocks/CU
// (72 KB LDS each, two independent barrier domains), XCD swizzle.
#define BUF_SHORTS 12288

#define STAGE(sl, q_)                                                                 \
    {                                                                                 \
        unsigned short* bufq = Bufs + (q_) * BUF_SHORTS;                              \
        const unsigned short* bsrc = wt + (size_t)(sl) * 8192;                        \
        _Pragma("unroll")                                                             \
        for (int t = 0; t < 3; ++t) {                                                 \
            int u = wave * 3 + t;            /* 0..23: u<16 = B, u>=16 = A */         \
            if (u < 16) {                                                             \
                int boff = u * 512 + lane * 8;                                        \
                __builtin_amdgcn_global_load_lds((g_u32_t*)(bsrc + boff),             \
                                                 (lds_u32_t*)(bufq + boff), 16, 0, 0);\
            } else {                                                                  \
                int idx = u - 16;            /* chunk 0..7 */                         \
                int ia  = (sl) * 8 + idx;                                             \
                int c_  = (ia * 7282) >> 16;                                          \
                int i9_ = ia - c_ * 9;                                                \
                int kh_ = (i9_ * 11) >> 5;                                            \
                int kw_ = i9_ - kh_ * 3;                                              \
                const unsigned short* asrc = ft +                                     \
                    (((size_t)(c_ * 8 + b) * PLANE16 + (y + kh_) * 66 + kw_) << 3)    \
                    + lane * 8;                                                       \
                unsigned short* adst = bufq + 8192 + idx * 512 + lane * 8;            \
                __builtin_amdgcn_global_load_lds((g_u32_t*)asrc, (lds_u32_t*)adst,    \
                                                 16, 0, 0);                           \
            }                                                                         \
        }                                                                             \
    }

#define COMPUTE(q_)                                                                   \
    {                                                                                 \
        const unsigned short* bufr = Bufs + (q_) * BUF_SHORTS;                        \
        const unsigned short* Ab = bufr + 8192 + iloc * 512;                          \
        const unsigned short* Bb = bufr + iloc * 1024 + nh * 512;                     \
        short8 a0 = *(const short8*)(Ab + l32 * 8);                                   \
        short8 a1 = *(const short8*)(Ab + (32 + l32) * 8);                            \
        short8 b0 = *(const short8*)(Bb + l32 * 8);                                   \
        short8 b1 = *(const short8*)(Bb + 256 + l32 * 8);                             \
        acc00 = __builtin_amdgcn_mfma_f32_32x32x16_bf16(a0, b0, acc00, 0, 0, 0);      \
        acc01 = __builtin_amdgcn_mfma_f32_32x32x16_bf16(a0, b1, acc01, 0, 0, 0);      \
        acc10 = __builtin_amdgcn_mfma_f32_32x32x16_bf16(a1, b0, acc10, 0, 0, 0);      \
        acc11 = __builtin_amdgcn_mfma_f32_32x32x16_bf16(a1, b1, acc11, 0, 0, 0);      \
    }

#define PHASE(q_, n_, stagesl, dostage_)                                              \
    {                                                                                 \
        asm volatile("s_waitcnt vmcnt(" #n_ ")" ::: "memory");                        \
        __builtin_amdgcn_s_barrier();                                                 \
        asm volatile("" ::: "memory");                                                \
        __builtin_amdgcn_s_setprio(1);                                                \
        COMPUTE(q_)                                                                   \
        __builtin_amdgcn_s_setprio(0);                                                \
        asm volatile("" ::: "memory");                                                \
        __builtin_amdgcn_s_barrier();                                                 \
        asm volatile("" ::: "memory");                                                \
        if (dostage_) STAGE(stagesl, q_);                                             \
    }

// Epilogue reduce helpers: conflict-free float4 layout (lane-stride 16 B).
#define DUMPA(base_, A_)                                                              \
    {   float4* s4 = (float4*)(red + (base_));                                        \
        _Pragma("unroll")                                                             \
        for (int c = 0; c < 4; ++c)                                                   \
            s4[c * 64 + lane] = make_float4(A_[4*c], A_[4*c+1], A_[4*c+2], A_[4*c+3]); }
#define ADDA(base_, A_)                                                               \
    {   const float4* s4 = (const float4*)(red + (base_));                            \
        _Pragma("unroll")                                                             \
        for (int c = 0; c < 4; ++c) {                                                 \
            float4 rv = s4[c * 64 + lane];                                            \
            A_[4*c] += rv.x; A_[4*c+1] += rv.y; A_[4*c+2] += rv.z; A_[4*c+3] += rv.w; } }

__global__ __launch_bounds__(512, 4)
void convkan_gemm(const unsigned short* __restrict__ ft,
                  const unsigned short* __restrict__ wt,
                  const float* __restrict__ bias,
                  float* __restrict__ out) {
    extern __shared__ unsigned short Bufs[];     // 3 x 12288 shorts = 72 KB

    const int tid  = threadIdx.x;
    const int blk  = blockIdx.x;                 // 0..511
    const int mb   = ((blk & 7) << 6) | (blk >> 3);  // XCD swizzle: XCD owns image
    const int lane = tid & 63;
    const int wave = tid >> 6;                   // 0..7
    const int kq   = wave >> 1;                  // K-quarter 0..3
    const int nh   = wave & 1;                   // n-half (64 ch)
    const int l32  = lane & 31;
    const int h    = lane >> 5;                  // k-half within MFMA K16
    const int iloc = (kq << 1) + h;              // e-chunk this half-wave consumes

    const int b = mb >> 6;                       // image 0..7
    const int y = mb & 63;                       // line 0..63

    f32x16 acc00, acc01, acc10, acc11;
#pragma unroll
    for (int e = 0; e < 16; ++e) { acc00[e] = 0.f; acc01[e] = 0.f; acc10[e] = 0.f; acc11[e] = 0.f; }

    // prologue: fill the 3-deep pipeline
    STAGE(0, 0);
    STAGE(1, 1);
    STAGE(2, 2);

    // steady state: phases 0..68 stage slabs 3..71
    for (int it3 = 0; it3 < 23; ++it3) {
        const int it = it3 * 3;
        PHASE(0, 6, it + 3, true)
        PHASE(1, 6, it + 4, true)
        PHASE(2, 6, it + 5, true)
    }
    // tail: phases 69, 70, 71 — drain pipeline
    PHASE(0, 6, 0, false)
    PHASE(1, 3, 0, false)
    PHASE(2, 0, 0, false)

    // ---- K-partial reduction across kq (3 rounds via LDS), then store ----
    __syncthreads();
    float* red = (float*)Bufs;

    if (kq >= 2) { DUMPA(((nh << 1) + (kq - 2)) * 2048,        acc00);
                   DUMPA(((nh << 1) + (kq - 2)) * 2048 + 1024, acc01); }
    __syncthreads();
    if (kq < 2)  { ADDA(((nh << 1) + kq) * 2048,        acc00);
                   ADDA(((nh << 1) + kq) * 2048 + 1024, acc01); }
    __syncthreads();
    if (kq >= 2) { DUMPA(((nh << 1) + (kq - 2)) * 2048,        acc10);
                   DUMPA(((nh << 1) + (kq - 2)) * 2048 + 1024, acc11); }
    __syncthreads();
    if (kq < 2)  { ADDA(((nh << 1) + kq) * 2048,        acc10);
                   ADDA(((nh << 1) + kq) * 2048 + 1024, acc11); }
    __syncthreads();
    if (kq == 1) { DUMPA(nh * 4096,        acc00); DUMPA(nh * 4096 + 1024, acc01);
                   DUMPA(nh * 4096 + 2048, acc10); DUMPA(nh * 4096 + 3072, acc11); }
    __syncthreads();
    if (kq == 0) {
        ADDA(nh * 4096,        acc00); ADDA(nh * 4096 + 1024, acc01);
        ADDA(nh * 4096 + 2048, acc10); ADDA(nh * 4096 + 3072, acc11);

        const int ncol = nh * 64 + l32;
        const float bv0 = bias[ncol];
        const float bv1 = bias[ncol + 32];
        const int prow = mb * 64;                // output pixel-row base
#pragma unroll
        for (int r = 0; r < 16; ++r) {
            int mrow = (r & 3) + ((r >> 2) << 3) + 4 * h;
            float* p = out + (size_t)(prow + mrow) * 128 + ncol;
            p[0]  = acc00[r] + bv0;
            p[32] = acc01[r] + bv1;
            float* p2 = out + (size_t)(prow + 32 + mrow) * 128 + ncol;
            p2[0]  = acc10[r] + bv0;
            p2[32] = acc11[r] + bv1;
        }
    }
}

extern "C" void kernel_launch(void* const* d_in, const int* in_sizes, int n_in,
                              void* d_out, int out_size, void* d_ws, size_t ws_size,
                              hipStream_t stream) {
    (void)in_sizes; (void)n_in; (void)ws_size; (void)out_size;
    const float* x        = (const float*)d_in[0];
    const float* base_w   = (const float*)d_in[1];
    const float* spline_w = (const float*)d_in[2];
    const float* bias     = (const float*)d_in[3];
    float* out = (float*)d_out;

    unsigned short* ft = (unsigned short*)d_ws;      // 35.68 MB halo features
    unsigned short* wt = ft + FT2_SHORTS;            // 1.18 MB tiled B (slab-major)

    hipLaunchKernelGGL(prep_all, dim3(2048), dim3(256), 0, stream,
                       x, base_w, spline_w, ft, wt);

    const int shmem = 3 * BUF_SHORTS * 2;            // 72 KB -> 2 blocks/CU
    (void)hipFuncSetAttribute((const void*)convkan_gemm,
                              hipFuncAttributeMaxDynamicSharedMemorySize, shmem);
    hipLaunchKernelGGL(convkan_gemm, dim3(512), dim3(512), shmem, stream,
                       ft, wt, bias, out);
}